// Round 12
// baseline (197.404 us; speedup 1.0000x reference)
//
#include <hip/hip_runtime.h>

typedef float f32x4 __attribute__((ext_vector_type(4)));
typedef float f32x2 __attribute__((ext_vector_type(2)));

#define T_LEN   262144
#define NTAG    128
#define LCH     4
#define BURN    8
#define NSTEP   (LCH + BURN)       // 12
#define NCHUNK  (T_LEN / LCH)      // 65536
#define NWAVE   (NCHUNK / 16)      // 4096
#define NFWDB   (NWAVE / 4)        // 1024
#define NPREPB  2048
#define NSCOREB 256
#define C9      6.23832462503951f  // 9 ln2 (fallback path scale)

// ===========================================================================
// FAST PATH
// E layout: row = 128 fp8 bytes; tag (16rt+4g+r) at byte h*64+g*16+rtl*4+r
// (h=rt>>2, rtl=rt&3). Lane (col,g) reads 2x16B at row*128+g*16 (+64); a
// wave instruction covers 16 rows x 64B fully-consumed aligned segments.
// ===========================================================================

// ---- prep: E = fp8(exp(emit-1)) + path score + A-fragment setup -----------
__global__ __launch_bounds__(256) void crf_prep(
    const float* __restrict__ emit, const int* __restrict__ y,
    const float* __restrict__ trans, const float* __restrict__ strans,
    const float* __restrict__ etrans, unsigned* __restrict__ Ed,
    uint4* __restrict__ q4, double* __restrict__ ws)
{
  const int gid    = blockIdx.x * 256 + threadIdx.x;
  const int stride = NPREPB * 256;                 // 524288
  const float4* __restrict__ em4 = (const float4*)emit;

  // phase 1: streaming convert — exactly 16 iter/thread, deep load batch
#pragma unroll 16
  for (int idx = gid; idx < T_LEN * 32; idx += stride) {
    const float4 v = em4[idx];
    const float e0 = __expf(v.x - 1.0f), e1 = __expf(v.y - 1.0f);
    const float e2 = __expf(v.z - 1.0f), e3 = __expf(v.w - 1.0f);
    unsigned d = (unsigned)__builtin_amdgcn_cvt_pk_fp8_f32(e0, e1, 0, false);
    d = (unsigned)__builtin_amdgcn_cvt_pk_fp8_f32(e2, e3, (int)d, true);
    const int q = idx & 31, row = idx >> 5;
    const int dd = ((q >> 4) << 4) | ((q & 3) << 2) | ((q >> 2) & 3);
    Ed[(row << 5) + dd] = d;
  }

  // phase 2: supervised path score (<=1 element per thread)
  {
    float v = 0.f;
    for (int t = gid; t < T_LEN - 1; t += stride) {
      const int yt = y[t], yn = y[t + 1];
      v += trans[yt * NTAG + yn] + emit[(size_t)t * NTAG + yt];
    }
    if (gid == 0) {
      const int yl = y[T_LEN - 1];
      v += strans[y[0]] + etrans[yl] + emit[(size_t)(T_LEN - 1) * NTAG + yl];
    }
#pragma unroll
    for (int off = 1; off < 64; off <<= 1) v += __shfl_xor(v, off, 64);
    if ((threadIdx.x & 63) == 0) atomicAdd(&ws[1], (double)v);
  }

  // phase 3: A = fp8(exp(trans)) fragments (block 0, wave 0)
  if (blockIdx.x == 0 && threadIdx.x < 64) {
    const int l = threadIdx.x, col = l & 15, grp = l >> 4;
    for (int rt = 0; rt < 8; ++rt) {
      const int outtag = 16 * rt + col;
      for (int kp = 0; kp < 2; ++kp) {
        unsigned r[4];
        for (int h = 0; h < 2; ++h) {
          const int kt = kp * 2 + h;
          float qv[8];
          for (int j = 0; j < 8; ++j) {
            const int k = 32 * kt + 4 * grp + (j & 3) + 16 * (j >> 2);
            qv[j] = __expf(trans[k * NTAG + outtag]);
          }
          unsigned lo = (unsigned)__builtin_amdgcn_cvt_pk_fp8_f32(qv[0], qv[1], 0, false);
          lo = (unsigned)__builtin_amdgcn_cvt_pk_fp8_f32(qv[2], qv[3], (int)lo, true);
          unsigned hi = (unsigned)__builtin_amdgcn_cvt_pk_fp8_f32(qv[4], qv[5], 0, false);
          hi = (unsigned)__builtin_amdgcn_cvt_pk_fp8_f32(qv[6], qv[7], (int)hi, true);
          r[h * 2] = lo; r[h * 2 + 1] = hi;
        }
        q4[(rt * 2 + kp) * 64 + l] = make_uint4(r[0], r[1], r[2], r[3]);
      }
    }
  }
}

// ---- main: wave-autonomous recurrence on fp8 E ----------------------------
__global__ __launch_bounds__(256, 2) void crf_main(
    const float* __restrict__ emit, const float* __restrict__ strans,
    const float* __restrict__ etrans, const unsigned char* __restrict__ Eb,
    const uint4* __restrict__ q4, double* __restrict__ ws,
    float* __restrict__ out)
{
  const int w_id = threadIdx.x >> 6;
  const int l    = threadIdx.x & 63;
  const int col  = l & 15;
  const int g    = l >> 4;
  const int gw   = blockIdx.x * 4 + w_id;
  const int gc   = gw * 16 + col;

  // A fragments
  long a[8][4];
#pragma unroll
  for (int rt = 0; rt < 8; ++rt)
#pragma unroll
    for (int kp = 0; kp < 2; ++kp) {
      uint4 v = q4[(rt * 2 + kp) * 64 + l];
      a[rt][2 * kp]     = (long)(((unsigned long long)v.y << 32) | v.x);
      a[rt][2 * kp + 1] = (long)(((unsigned long long)v.w << 32) | v.z);
    }

  // init state: chunk 0 exact; others p = 1
  float m0 = 0.f;
  long b[4];
  {
    float u[8][4];
    if (gw == 0) {
      float vm = -1e30f;
#pragma unroll
      for (int rt = 0; rt < 8; ++rt)
#pragma unroll
        for (int r = 0; r < 4; ++r) {
          const int tag = 16 * rt + 4 * g + r;
          u[rt][r] = (col == 0) ? (strans[tag] + emit[tag]) : 0.f;
          vm = fmaxf(vm, u[rt][r]);
        }
      vm = fmaxf(vm, __shfl_xor(vm, 16, 64));
      vm = fmaxf(vm, __shfl_xor(vm, 32, 64));
      m0 = vm;
#pragma unroll
      for (int rt = 0; rt < 8; ++rt)
#pragma unroll
        for (int r = 0; r < 4; ++r)
          u[rt][r] = (col == 0) ? __expf(u[rt][r] - vm) : 1.0f;
    } else {
#pragma unroll
      for (int rt = 0; rt < 8; ++rt)
#pragma unroll
        for (int r = 0; r < 4; ++r) u[rt][r] = 1.0f;
    }
#pragma unroll
    for (int kt = 0; kt < 4; ++kt) {
      unsigned lo = (unsigned)__builtin_amdgcn_cvt_pk_fp8_f32(u[2*kt][0], u[2*kt][1], 0, false);
      lo = (unsigned)__builtin_amdgcn_cvt_pk_fp8_f32(u[2*kt][2], u[2*kt][3], (int)lo, true);
      unsigned hi = (unsigned)__builtin_amdgcn_cvt_pk_fp8_f32(u[2*kt+1][0], u[2*kt+1][1], 0, false);
      hi = (unsigned)__builtin_amdgcn_cvt_pk_fp8_f32(u[2*kt+1][2], u[2*kt+1][3], (int)hi, true);
      b[kt] = (long)(((unsigned long long)hi << 32) | lo);
    }
  }

  // depth-4 prefetch (2 x uint4 per row per lane); clamp negative burn rows
  const int t0 = (gc == 0) ? 1 : (gc * LCH - BURN);
  uint4 pf[4][2];
#pragma unroll
  for (int d = 0; d < 4; ++d) {
    const int tr = max(t0 + d, 0);
    const unsigned char* p = Eb + ((size_t)tr << 7) + g * 16;
    pf[d][0] = *(const uint4*)p;
    pf[d][1] = *(const uint4*)(p + 64);
  }

  float acc = 0.f;

#pragma unroll
  for (int s = 0; s < NSTEP; ++s) {
    // unpack E
    float e[8][4];
#pragma unroll
    for (int h = 0; h < 2; ++h) {
      const uint4 P = pf[s & 3][h];
      const unsigned dws[4] = {P.x, P.y, P.z, P.w};
#pragma unroll
      for (int j = 0; j < 4; ++j) {
        const f32x2 lo = __builtin_amdgcn_cvt_pk_f32_fp8((int)dws[j], false);
        const f32x2 hi = __builtin_amdgcn_cvt_pk_f32_fp8((int)dws[j], true);
        e[4 * h + j][0] = lo[0];
        e[4 * h + j][1] = lo[1];
        e[4 * h + j][2] = hi[0];
        e[4 * h + j][3] = hi[1];
      }
    }
    // prefetch row s+4
    if (s < NSTEP - 4) {
      const int tr = max(t0 + s + 4, 0);
      const unsigned char* p = Eb + ((size_t)tr << 7) + g * 16;
      pf[s & 3][0] = *(const uint4*)p;
      pf[s & 3][1] = *(const uint4*)(p + 64);
    }

    // c = A x b
    f32x4 c[8];
#pragma unroll
    for (int rt = 0; rt < 8; ++rt) c[rt] = (f32x4){0.f, 0.f, 0.f, 0.f};
#pragma unroll
    for (int kt = 0; kt < 4; ++kt)
#pragma unroll
      for (int rt = 0; rt < 8; ++rt)
        c[rt] = __builtin_amdgcn_mfma_f32_16x16x32_fp8_fp8(a[rt][kt], b[kt], c[rt], 0, 0, 0);

    // w = c * E; per-step rescale; dc = log(vm) (+1/step folded at end)
    float wv[8][4];
    float vm = -1e30f;
#pragma unroll
    for (int rt = 0; rt < 8; ++rt)
#pragma unroll
      for (int r = 0; r < 4; ++r) {
        wv[rt][r] = c[rt][r] * e[rt][r];
        vm = fmaxf(vm, wv[rt][r]);
      }
    vm = fmaxf(vm, __shfl_xor(vm, 16, 64));
    vm = fmaxf(vm, __shfl_xor(vm, 32, 64));
    const bool on = (gc == 0) ? (s <= LCH - 2) : (s >= BURN);
    if (on) acc += __logf(vm);
    const float rinv = __frcp_rn(vm);
#pragma unroll
    for (int kt = 0; kt < 4; ++kt) {
      const float s0 = wv[2*kt][0] * rinv,   s1 = wv[2*kt][1] * rinv;
      const float s2 = wv[2*kt][2] * rinv,   s3 = wv[2*kt][3] * rinv;
      const float s4 = wv[2*kt+1][0] * rinv, s5 = wv[2*kt+1][1] * rinv;
      const float s6 = wv[2*kt+1][2] * rinv, s7 = wv[2*kt+1][3] * rinv;
      unsigned lo = (unsigned)__builtin_amdgcn_cvt_pk_fp8_f32(s0, s1, 0, false);
      lo = (unsigned)__builtin_amdgcn_cvt_pk_fp8_f32(s2, s3, (int)lo, true);
      unsigned hi = (unsigned)__builtin_amdgcn_cvt_pk_fp8_f32(s4, s5, 0, false);
      hi = (unsigned)__builtin_amdgcn_cvt_pk_fp8_f32(s6, s7, (int)hi, true);
      b[kt] = (long)(((unsigned long long)hi << 32) | lo);
    }

    if (s == NSTEP - 1 && gw == NWAVE - 1) {
      float lse = 0.f;
#pragma unroll
      for (int rt = 0; rt < 8; ++rt)
#pragma unroll
        for (int r = 0; r < 4; ++r)
          lse += (wv[rt][r] * rinv) * __expf(etrans[16 * rt + 4 * g + r]);
      lse += __shfl_xor(lse, 16, 64);
      lse += __shfl_xor(lse, 32, 64);
      if (l == 15) atomicAdd(&ws[2], (double)lse);
    }
  }

  // per-chunk compensation: E carries e^-1 on each counted step.
  // chunk 0: dc_0=m0 + (LCH-1) counted steps; others: LCH counted steps.
  const float accf = acc + ((gc == 0) ? (m0 + (float)(LCH - 1)) : (float)LCH);
  float av = (g == 0) ? accf : 0.f;
#pragma unroll
  for (int off = 1; off < 64; off <<= 1) av += __shfl_xor(av, off, 64);
  if (l == 0) atomicAdd(&ws[0], (double)av);

  // completion ticket
  __syncthreads();
  if (threadIdx.x == 0) {
    __threadfence();
    const unsigned t = atomicAdd((unsigned*)&ws[3], 1u);
    if (t == NFWDB - 1) {
      const double d0 = atomicAdd(&ws[0], 0.0);
      const double d1 = atomicAdd(&ws[1], 0.0);
      const double d2 = atomicAdd(&ws[2], 0.0);
      out[0] = (float)(d0 + log(d2) - d1);
    }
  }
}

// ===========================================================================
// FALLBACK PATH (only if ws_size too small) — emit-direct, same parameters
// ===========================================================================
__global__ void crf_setup(const float* __restrict__ trans, uint4* __restrict__ q4)
{
  const int l = threadIdx.x, col = l & 15, grp = l >> 4;
  for (int rt = 0; rt < 8; ++rt) {
    const int outtag = 16 * rt + col;
    for (int kp = 0; kp < 2; ++kp) {
      unsigned r[4];
      for (int h = 0; h < 2; ++h) {
        const int kt = kp * 2 + h;
        float q[8];
        for (int j = 0; j < 8; ++j) {
          const int k = 32 * kt + 4 * grp + (j & 3) + 16 * (j >> 2);
          q[j] = __expf(trans[k * NTAG + outtag]);
        }
        unsigned lo = (unsigned)__builtin_amdgcn_cvt_pk_fp8_f32(q[0], q[1], 0, false);
        lo = (unsigned)__builtin_amdgcn_cvt_pk_fp8_f32(q[2], q[3], (int)lo, true);
        unsigned hi = (unsigned)__builtin_amdgcn_cvt_pk_fp8_f32(q[4], q[5], 0, false);
        hi = (unsigned)__builtin_amdgcn_cvt_pk_fp8_f32(q[6], q[7], (int)hi, true);
        r[h * 2] = lo; r[h * 2 + 1] = hi;
      }
      q4[(rt * 2 + kp) * 64 + l] = make_uint4(r[0], r[1], r[2], r[3]);
    }
  }
}

__global__ __launch_bounds__(256, 2) void crf_fwd(
    const float* __restrict__ emit, const float* __restrict__ strans,
    const float* __restrict__ etrans, const uint4* __restrict__ q4,
    double* __restrict__ ws)
{
  const int w_id = threadIdx.x >> 6, l = threadIdx.x & 63;
  const int col = l & 15, grp = l >> 4;
  const int gw = blockIdx.x * 4 + w_id, gc = gw * 16 + col;
  long a[8][4];
#pragma unroll
  for (int rt = 0; rt < 8; ++rt)
#pragma unroll
    for (int kp = 0; kp < 2; ++kp) {
      uint4 v = q4[(rt * 2 + kp) * 64 + l];
      a[rt][2 * kp]     = (long)(((unsigned long long)v.y << 32) | v.x);
      a[rt][2 * kp + 1] = (long)(((unsigned long long)v.w << 32) | v.z);
    }
  float m0 = 0.f;
  long b[4];
  {
    float u[8][4];
    if (gw == 0) {
      float vm = -1e30f;
#pragma unroll
      for (int rt = 0; rt < 8; ++rt)
#pragma unroll
        for (int r = 0; r < 4; ++r) {
          const int tag = 16 * rt + 4 * grp + r;
          u[rt][r] = (col == 0) ? (strans[tag] + emit[tag]) : 0.f;
          vm = fmaxf(vm, u[rt][r]);
        }
      vm = fmaxf(vm, __shfl_xor(vm, 16, 64));
      vm = fmaxf(vm, __shfl_xor(vm, 32, 64));
      m0 = vm;
#pragma unroll
      for (int rt = 0; rt < 8; ++rt)
#pragma unroll
        for (int r = 0; r < 4; ++r)
          u[rt][r] = (col == 0) ? __expf(u[rt][r] - vm) : 1.0f;
    } else {
#pragma unroll
      for (int rt = 0; rt < 8; ++rt)
#pragma unroll
        for (int r = 0; r < 4; ++r) u[rt][r] = 1.0f;
    }
#pragma unroll
    for (int kt = 0; kt < 4; ++kt) {
      unsigned lo = (unsigned)__builtin_amdgcn_cvt_pk_fp8_f32(u[2*kt][0], u[2*kt][1], 0, false);
      lo = (unsigned)__builtin_amdgcn_cvt_pk_fp8_f32(u[2*kt][2], u[2*kt][3], (int)lo, true);
      unsigned hi = (unsigned)__builtin_amdgcn_cvt_pk_fp8_f32(u[2*kt+1][0], u[2*kt+1][1], 0, false);
      hi = (unsigned)__builtin_amdgcn_cvt_pk_fp8_f32(u[2*kt+1][2], u[2*kt+1][3], (int)hi, true);
      b[kt] = (long)(((unsigned long long)hi << 32) | lo);
    }
  }
  const int t0 = (gc == 0) ? 1 : (gc * LCH - BURN);
  float4 pf[2][8];
  {
    const float* e0 = emit + ((size_t)max(t0, 0) << 7) + 4 * grp;
    const float* e1 = emit + ((size_t)max(t0 + 1, 0) << 7) + 4 * grp;
#pragma unroll
    for (int rt = 0; rt < 8; ++rt) {
      pf[0][rt] = *(const float4*)(e0 + 16 * rt);
      pf[1][rt] = *(const float4*)(e1 + 16 * rt);
    }
  }
  float acc = 0.f;
#pragma unroll
  for (int s = 0; s < NSTEP; ++s) {
    float e[8][4];
#pragma unroll
    for (int rt = 0; rt < 8; ++rt) {
      e[rt][0] = __expf(pf[s & 1][rt].x - C9);
      e[rt][1] = __expf(pf[s & 1][rt].y - C9);
      e[rt][2] = __expf(pf[s & 1][rt].z - C9);
      e[rt][3] = __expf(pf[s & 1][rt].w - C9);
    }
    if (s < NSTEP - 2) {
      const float* ep = emit + ((size_t)max(t0 + s + 2, 0) << 7) + 4 * grp;
#pragma unroll
      for (int rt = 0; rt < 8; ++rt) pf[s & 1][rt] = *(const float4*)(ep + 16 * rt);
    }
    f32x4 c[8];
#pragma unroll
    for (int rt = 0; rt < 8; ++rt) c[rt] = (f32x4){0.f, 0.f, 0.f, 0.f};
#pragma unroll
    for (int kt = 0; kt < 4; ++kt)
#pragma unroll
      for (int rt = 0; rt < 8; ++rt)
        c[rt] = __builtin_amdgcn_mfma_f32_16x16x32_fp8_fp8(a[rt][kt], b[kt], c[rt], 0, 0, 0);
    float wv[8][4];
    float vm = -1e30f;
#pragma unroll
    for (int rt = 0; rt < 8; ++rt)
#pragma unroll
      for (int r = 0; r < 4; ++r) {
        wv[rt][r] = c[rt][r] * e[rt][r];
        vm = fmaxf(vm, wv[rt][r]);
      }
    vm = fmaxf(vm, __shfl_xor(vm, 16, 64));
    vm = fmaxf(vm, __shfl_xor(vm, 32, 64));
    const bool on = (gc == 0) ? (s <= LCH - 2) : (s >= BURN);
    if (on) acc += __logf(vm);
    const float rinv = __frcp_rn(vm);
#pragma unroll
    for (int kt = 0; kt < 4; ++kt) {
      const float s0 = wv[2*kt][0] * rinv,   s1 = wv[2*kt][1] * rinv;
      const float s2 = wv[2*kt][2] * rinv,   s3 = wv[2*kt][3] * rinv;
      const float s4 = wv[2*kt+1][0] * rinv, s5 = wv[2*kt+1][1] * rinv;
      const float s6 = wv[2*kt+1][2] * rinv, s7 = wv[2*kt+1][3] * rinv;
      unsigned lo = (unsigned)__builtin_amdgcn_cvt_pk_fp8_f32(s0, s1, 0, false);
      lo = (unsigned)__builtin_amdgcn_cvt_pk_fp8_f32(s2, s3, (int)lo, true);
      unsigned hi = (unsigned)__builtin_amdgcn_cvt_pk_fp8_f32(s4, s5, 0, false);
      hi = (unsigned)__builtin_amdgcn_cvt_pk_fp8_f32(s6, s7, (int)hi, true);
      b[kt] = (long)(((unsigned long long)hi << 32) | lo);
    }
    if (s == NSTEP - 1 && gw == NWAVE - 1) {
      float lse = 0.f;
#pragma unroll
      for (int rt = 0; rt < 8; ++rt)
#pragma unroll
        for (int r = 0; r < 4; ++r)
          lse += (wv[rt][r] * rinv) * __expf(etrans[16 * rt + 4 * grp + r]);
      lse += __shfl_xor(lse, 16, 64);
      lse += __shfl_xor(lse, 32, 64);
      if (l == 15) atomicAdd(&ws[2], (double)lse);
    }
  }
  const float accf = acc + ((gc == 0) ? (m0 + (float)(LCH - 1) * C9)
                                      : ((float)LCH * C9));
  float av = (grp == 0) ? accf : 0.f;
#pragma unroll
  for (int off = 1; off < 64; off <<= 1) av += __shfl_xor(av, off, 64);
  if (l == 0) atomicAdd(&ws[0], (double)av);
}

__global__ void crf_score(const float* __restrict__ emit, const int* __restrict__ y,
                          const float* __restrict__ trans, const float* __restrict__ strans,
                          const float* __restrict__ etrans, double* __restrict__ ws)
{
  __shared__ float sred[4];
  int idx0 = blockIdx.x * 256 + threadIdx.x;
  float v = 0.f;
  for (int t = idx0; t < T_LEN - 1; t += NSCOREB * 256) {
    int yt = y[t], yn = y[t + 1];
    v += trans[yt * NTAG + yn] + emit[(size_t)t * NTAG + yt];
  }
  if (idx0 == 0) {
    int yl = y[T_LEN - 1];
    v += strans[y[0]] + etrans[yl] + emit[(size_t)(T_LEN - 1) * NTAG + yl];
  }
#pragma unroll
  for (int off = 1; off < 64; off <<= 1) v += __shfl_xor(v, off, 64);
  if ((threadIdx.x & 63) == 0) sred[threadIdx.x >> 6] = v;
  __syncthreads();
  if (threadIdx.x == 0)
    atomicAdd(&ws[1], (double)(sred[0] + sred[1] + sred[2] + sred[3]));
}

__global__ void crf_final(const double* __restrict__ ws, float* __restrict__ out)
{
  out[0] = (float)(ws[0] + log(ws[2]) - ws[1]);
}

// ---------------------------------------------------------------------------
extern "C" void kernel_launch(void* const* d_in, const int* in_sizes, int n_in,
                              void* d_out, int out_size, void* d_ws, size_t ws_size,
                              hipStream_t stream)
{
  const float* emit   = (const float*)d_in[0];
  const int*   y      = (const int*)d_in[1];
  const float* trans  = (const float*)d_in[2];
  const float* strans = (const float*)d_in[3];
  const float* etrans = (const float*)d_in[4];
  float*  out = (float*)d_out;
  double* ws  = (double*)d_ws;
  uint4*  q4  = (uint4*)((char*)d_ws + 128);             // 16 KB A-fragments
  unsigned* Ed = (unsigned*)((char*)d_ws + 128 + 16384); // 33.55 MB fp8 E

  const size_t need = 128 + 16384 + (size_t)T_LEN * NTAG;

  hipMemsetAsync(ws, 0, 8 * sizeof(double), stream);

  if (ws_size >= need) {
    crf_prep<<<dim3(NPREPB), dim3(256), 0, stream>>>(
        emit, y, trans, strans, etrans, Ed, q4, ws);
    crf_main<<<dim3(NFWDB), dim3(256), 0, stream>>>(
        emit, strans, etrans, (const unsigned char*)Ed, q4, ws, out);
  } else {
    crf_setup<<<dim3(1), dim3(64), 0, stream>>>(trans, q4);
    crf_score<<<dim3(NSCOREB), dim3(256), 0, stream>>>(emit, y, trans, strans, etrans, ws);
    crf_fwd  <<<dim3(NFWDB), dim3(256), 0, stream>>>(emit, strans, etrans, q4, ws);
    crf_final<<<dim3(1), dim3(1), 0, stream>>>(ws, out);
  }
}

// Round 13
// 124.855 us; speedup vs baseline: 1.5811x; 1.5811x over previous
//
#include <hip/hip_runtime.h>

typedef float f32x4 __attribute__((ext_vector_type(4)));
typedef float f32x2 __attribute__((ext_vector_type(2)));

#define T_LEN   262144
#define NTAG    128
#define LCH     8
#define BURN    8
#define NSTEP   (LCH + BURN)       // 16
#define NCHUNK  (T_LEN / LCH)      // 32768
#define NWAVE   (NCHUNK / 16)      // 2048
#define NFWDB   (NWAVE / 4)        // 512
#define NPREPB  4096
#define NITER   8                  // 4096*256*8 == T_LEN*32 exactly
#define NSCOREB 256
#define C9      6.23832462503951f  // 9 ln2 (fallback path scale)

// ===========================================================================
// FAST PATH
// E layout: row = 128 fp8 bytes; tag (16rt+4g+r) at byte h*64+g*16+rtl*4+r
// (h=rt>>2, rtl=rt&3). Lane (col,g) reads 2x16B at row*128+g*16 (+64); a
// wave instruction covers 16 rows x 64B fully-consumed aligned segments.
// ===========================================================================

// ---- prep: E = fp8(exp(emit-1)) + path score + A-fragment setup -----------
// Guard-free batched loads: each thread does exactly NITER float4 loads,
// issued back-to-back into registers (compiler barrier stops sinking), then
// transforms and stores. This is the MLP fix for the ~1.4 TB/s read cap.
__global__ __launch_bounds__(256) void crf_prep(
    const float* __restrict__ emit, const int* __restrict__ y,
    const float* __restrict__ trans, const float* __restrict__ strans,
    const float* __restrict__ etrans, unsigned* __restrict__ Ed,
    uint4* __restrict__ q4, double* __restrict__ ws)
{
  const int gid    = blockIdx.x * 256 + threadIdx.x;   // 0..1048575
  const int stride = NPREPB * 256;                     // 1048576
  const float4* __restrict__ em4 = (const float4*)emit;

  // phase 1a: issue all NITER loads (no guards, no consumption)
  float4 v[NITER];
#pragma unroll
  for (int i = 0; i < NITER; ++i) v[i] = em4[gid + i * stride];
  asm volatile("" ::: "memory");   // keep loads batched ahead of compute

  // phase 1b: transform + permuted store
#pragma unroll
  for (int i = 0; i < NITER; ++i) {
    const int idx = gid + i * stride;
    const float e0 = __expf(v[i].x - 1.0f), e1 = __expf(v[i].y - 1.0f);
    const float e2 = __expf(v[i].z - 1.0f), e3 = __expf(v[i].w - 1.0f);
    unsigned d = (unsigned)__builtin_amdgcn_cvt_pk_fp8_f32(e0, e1, 0, false);
    d = (unsigned)__builtin_amdgcn_cvt_pk_fp8_f32(e2, e3, (int)d, true);
    const int q = idx & 31, row = idx >> 5;
    const int dd = ((q >> 4) << 4) | ((q & 3) << 2) | ((q >> 2) & 3);
    Ed[(row << 5) + dd] = d;
  }

  // phase 2: supervised path score (<=1 element per thread)
  {
    float sv = 0.f;
    if (gid < T_LEN - 1) {
      const int yt = y[gid], yn = y[gid + 1];
      sv = trans[yt * NTAG + yn] + emit[(size_t)gid * NTAG + yt];
    }
    if (gid == 0) {
      const int yl = y[T_LEN - 1];
      sv += strans[y[0]] + etrans[yl] + emit[(size_t)(T_LEN - 1) * NTAG + yl];
    }
#pragma unroll
    for (int off = 1; off < 64; off <<= 1) sv += __shfl_xor(sv, off, 64);
    if ((threadIdx.x & 63) == 0 && sv != 0.f) atomicAdd(&ws[1], (double)sv);
  }

  // phase 3: A = fp8(exp(trans)) fragments (block 0, wave 0)
  if (blockIdx.x == 0 && threadIdx.x < 64) {
    const int l = threadIdx.x, col = l & 15, grp = l >> 4;
    for (int rt = 0; rt < 8; ++rt) {
      const int outtag = 16 * rt + col;
      for (int kp = 0; kp < 2; ++kp) {
        unsigned r[4];
        for (int h = 0; h < 2; ++h) {
          const int kt = kp * 2 + h;
          float qv[8];
          for (int j = 0; j < 8; ++j) {
            const int k = 32 * kt + 4 * grp + (j & 3) + 16 * (j >> 2);
            qv[j] = __expf(trans[k * NTAG + outtag]);
          }
          unsigned lo = (unsigned)__builtin_amdgcn_cvt_pk_fp8_f32(qv[0], qv[1], 0, false);
          lo = (unsigned)__builtin_amdgcn_cvt_pk_fp8_f32(qv[2], qv[3], (int)lo, true);
          unsigned hi = (unsigned)__builtin_amdgcn_cvt_pk_fp8_f32(qv[4], qv[5], 0, false);
          hi = (unsigned)__builtin_amdgcn_cvt_pk_fp8_f32(qv[6], qv[7], (int)hi, true);
          r[h * 2] = lo; r[h * 2 + 1] = hi;
        }
        q4[(rt * 2 + kp) * 64 + l] = make_uint4(r[0], r[1], r[2], r[3]);
      }
    }
  }
}

// ---- main: wave-autonomous recurrence on fp8 E (R11 proven config) --------
__global__ __launch_bounds__(256, 2) void crf_main(
    const float* __restrict__ emit, const float* __restrict__ strans,
    const float* __restrict__ etrans, const unsigned char* __restrict__ Eb,
    const uint4* __restrict__ q4, double* __restrict__ ws,
    float* __restrict__ out)
{
  const int w_id = threadIdx.x >> 6;
  const int l    = threadIdx.x & 63;
  const int col  = l & 15;
  const int g    = l >> 4;
  const int gw   = blockIdx.x * 4 + w_id;
  const int gc   = gw * 16 + col;

  // A fragments
  long a[8][4];
#pragma unroll
  for (int rt = 0; rt < 8; ++rt)
#pragma unroll
    for (int kp = 0; kp < 2; ++kp) {
      uint4 v = q4[(rt * 2 + kp) * 64 + l];
      a[rt][2 * kp]     = (long)(((unsigned long long)v.y << 32) | v.x);
      a[rt][2 * kp + 1] = (long)(((unsigned long long)v.w << 32) | v.z);
    }

  // init state: chunk 0 exact; others p = 1
  float m0 = 0.f;
  long b[4];
  {
    float u[8][4];
    if (gw == 0) {
      float vm = -1e30f;
#pragma unroll
      for (int rt = 0; rt < 8; ++rt)
#pragma unroll
        for (int r = 0; r < 4; ++r) {
          const int tag = 16 * rt + 4 * g + r;
          u[rt][r] = (col == 0) ? (strans[tag] + emit[tag]) : 0.f;
          vm = fmaxf(vm, u[rt][r]);
        }
      vm = fmaxf(vm, __shfl_xor(vm, 16, 64));
      vm = fmaxf(vm, __shfl_xor(vm, 32, 64));
      m0 = vm;
#pragma unroll
      for (int rt = 0; rt < 8; ++rt)
#pragma unroll
        for (int r = 0; r < 4; ++r)
          u[rt][r] = (col == 0) ? __expf(u[rt][r] - vm) : 1.0f;
    } else {
#pragma unroll
      for (int rt = 0; rt < 8; ++rt)
#pragma unroll
        for (int r = 0; r < 4; ++r) u[rt][r] = 1.0f;
    }
#pragma unroll
    for (int kt = 0; kt < 4; ++kt) {
      unsigned lo = (unsigned)__builtin_amdgcn_cvt_pk_fp8_f32(u[2*kt][0], u[2*kt][1], 0, false);
      lo = (unsigned)__builtin_amdgcn_cvt_pk_fp8_f32(u[2*kt][2], u[2*kt][3], (int)lo, true);
      unsigned hi = (unsigned)__builtin_amdgcn_cvt_pk_fp8_f32(u[2*kt+1][0], u[2*kt+1][1], 0, false);
      hi = (unsigned)__builtin_amdgcn_cvt_pk_fp8_f32(u[2*kt+1][2], u[2*kt+1][3], (int)hi, true);
      b[kt] = (long)(((unsigned long long)hi << 32) | lo);
    }
  }

  // depth-4 prefetch of E rows (2 x uint4 per row per lane); t0 >= 0 always
  const int t0 = (gc == 0) ? 1 : (gc * LCH - BURN);
  uint4 pf[4][2];
#pragma unroll
  for (int d = 0; d < 4; ++d) {
    const unsigned char* p = Eb + ((size_t)(t0 + d) << 7) + g * 16;
    pf[d][0] = *(const uint4*)p;
    pf[d][1] = *(const uint4*)(p + 64);
  }

  float acc = 0.f;

#pragma unroll
  for (int s = 0; s < NSTEP; ++s) {
    // unpack E
    float e[8][4];
#pragma unroll
    for (int h = 0; h < 2; ++h) {
      const uint4 P = pf[s & 3][h];
      const unsigned dws[4] = {P.x, P.y, P.z, P.w};
#pragma unroll
      for (int j = 0; j < 4; ++j) {
        const f32x2 lo = __builtin_amdgcn_cvt_pk_f32_fp8((int)dws[j], false);
        const f32x2 hi = __builtin_amdgcn_cvt_pk_f32_fp8((int)dws[j], true);
        e[4 * h + j][0] = lo[0];
        e[4 * h + j][1] = lo[1];
        e[4 * h + j][2] = hi[0];
        e[4 * h + j][3] = hi[1];
      }
    }
    // prefetch row s+4
    if (s < NSTEP - 4) {
      const unsigned char* p = Eb + ((size_t)(t0 + s + 4) << 7) + g * 16;
      pf[s & 3][0] = *(const uint4*)p;
      pf[s & 3][1] = *(const uint4*)(p + 64);
    }

    // c = A x b
    f32x4 c[8];
#pragma unroll
    for (int rt = 0; rt < 8; ++rt) c[rt] = (f32x4){0.f, 0.f, 0.f, 0.f};
#pragma unroll
    for (int kt = 0; kt < 4; ++kt)
#pragma unroll
      for (int rt = 0; rt < 8; ++rt)
        c[rt] = __builtin_amdgcn_mfma_f32_16x16x32_fp8_fp8(a[rt][kt], b[kt], c[rt], 0, 0, 0);

    // w = c * E; per-step rescale; dc = log(vm) (+1/step folded at end)
    float wv[8][4];
    float vm = -1e30f;
#pragma unroll
    for (int rt = 0; rt < 8; ++rt)
#pragma unroll
      for (int r = 0; r < 4; ++r) {
        wv[rt][r] = c[rt][r] * e[rt][r];
        vm = fmaxf(vm, wv[rt][r]);
      }
    vm = fmaxf(vm, __shfl_xor(vm, 16, 64));
    vm = fmaxf(vm, __shfl_xor(vm, 32, 64));
    const bool on = (gc == 0) ? (s <= LCH - 2) : (s >= BURN);
    if (on) acc += __logf(vm);
    const float rinv = __frcp_rn(vm);
#pragma unroll
    for (int kt = 0; kt < 4; ++kt) {
      const float s0 = wv[2*kt][0] * rinv,   s1 = wv[2*kt][1] * rinv;
      const float s2 = wv[2*kt][2] * rinv,   s3 = wv[2*kt][3] * rinv;
      const float s4 = wv[2*kt+1][0] * rinv, s5 = wv[2*kt+1][1] * rinv;
      const float s6 = wv[2*kt+1][2] * rinv, s7 = wv[2*kt+1][3] * rinv;
      unsigned lo = (unsigned)__builtin_amdgcn_cvt_pk_fp8_f32(s0, s1, 0, false);
      lo = (unsigned)__builtin_amdgcn_cvt_pk_fp8_f32(s2, s3, (int)lo, true);
      unsigned hi = (unsigned)__builtin_amdgcn_cvt_pk_fp8_f32(s4, s5, 0, false);
      hi = (unsigned)__builtin_amdgcn_cvt_pk_fp8_f32(s6, s7, (int)hi, true);
      b[kt] = (long)(((unsigned long long)hi << 32) | lo);
    }

    if (s == NSTEP - 1 && gw == NWAVE - 1) {
      float lse = 0.f;
#pragma unroll
      for (int rt = 0; rt < 8; ++rt)
#pragma unroll
        for (int r = 0; r < 4; ++r)
          lse += (wv[rt][r] * rinv) * __expf(etrans[16 * rt + 4 * g + r]);
      lse += __shfl_xor(lse, 16, 64);
      lse += __shfl_xor(lse, 32, 64);
      if (l == 15) atomicAdd(&ws[2], (double)lse);
    }
  }

  // per-chunk compensation: E carries e^-1 on each counted step.
  const float accf = acc + ((gc == 0) ? (m0 + (float)(LCH - 1)) : (float)LCH);
  float av = (g == 0) ? accf : 0.f;
#pragma unroll
  for (int off = 1; off < 64; off <<= 1) av += __shfl_xor(av, off, 64);
  if (l == 0) atomicAdd(&ws[0], (double)av);

  // completion ticket
  __syncthreads();
  if (threadIdx.x == 0) {
    __threadfence();
    const unsigned t = atomicAdd((unsigned*)&ws[3], 1u);
    if (t == NFWDB - 1) {
      const double d0 = atomicAdd(&ws[0], 0.0);
      const double d1 = atomicAdd(&ws[1], 0.0);
      const double d2 = atomicAdd(&ws[2], 0.0);
      out[0] = (float)(d0 + log(d2) - d1);
    }
  }
}

// ===========================================================================
// FALLBACK PATH (only if ws_size too small) — emit-direct
// ===========================================================================
__global__ void crf_setup(const float* __restrict__ trans, uint4* __restrict__ q4)
{
  const int l = threadIdx.x, col = l & 15, grp = l >> 4;
  for (int rt = 0; rt < 8; ++rt) {
    const int outtag = 16 * rt + col;
    for (int kp = 0; kp < 2; ++kp) {
      unsigned r[4];
      for (int h = 0; h < 2; ++h) {
        const int kt = kp * 2 + h;
        float q[8];
        for (int j = 0; j < 8; ++j) {
          const int k = 32 * kt + 4 * grp + (j & 3) + 16 * (j >> 2);
          q[j] = __expf(trans[k * NTAG + outtag]);
        }
        unsigned lo = (unsigned)__builtin_amdgcn_cvt_pk_fp8_f32(q[0], q[1], 0, false);
        lo = (unsigned)__builtin_amdgcn_cvt_pk_fp8_f32(q[2], q[3], (int)lo, true);
        unsigned hi = (unsigned)__builtin_amdgcn_cvt_pk_fp8_f32(q[4], q[5], 0, false);
        hi = (unsigned)__builtin_amdgcn_cvt_pk_fp8_f32(q[6], q[7], (int)hi, true);
        r[h * 2] = lo; r[h * 2 + 1] = hi;
      }
      q4[(rt * 2 + kp) * 64 + l] = make_uint4(r[0], r[1], r[2], r[3]);
    }
  }
}

__global__ __launch_bounds__(256, 2) void crf_fwd(
    const float* __restrict__ emit, const float* __restrict__ strans,
    const float* __restrict__ etrans, const uint4* __restrict__ q4,
    double* __restrict__ ws)
{
  const int w_id = threadIdx.x >> 6, l = threadIdx.x & 63;
  const int col = l & 15, grp = l >> 4;
  const int gw = blockIdx.x * 4 + w_id, gc = gw * 16 + col;
  long a[8][4];
#pragma unroll
  for (int rt = 0; rt < 8; ++rt)
#pragma unroll
    for (int kp = 0; kp < 2; ++kp) {
      uint4 v = q4[(rt * 2 + kp) * 64 + l];
      a[rt][2 * kp]     = (long)(((unsigned long long)v.y << 32) | v.x);
      a[rt][2 * kp + 1] = (long)(((unsigned long long)v.w << 32) | v.z);
    }
  float m0 = 0.f;
  long b[4];
  {
    float u[8][4];
    if (gw == 0) {
      float vm = -1e30f;
#pragma unroll
      for (int rt = 0; rt < 8; ++rt)
#pragma unroll
        for (int r = 0; r < 4; ++r) {
          const int tag = 16 * rt + 4 * grp + r;
          u[rt][r] = (col == 0) ? (strans[tag] + emit[tag]) : 0.f;
          vm = fmaxf(vm, u[rt][r]);
        }
      vm = fmaxf(vm, __shfl_xor(vm, 16, 64));
      vm = fmaxf(vm, __shfl_xor(vm, 32, 64));
      m0 = vm;
#pragma unroll
      for (int rt = 0; rt < 8; ++rt)
#pragma unroll
        for (int r = 0; r < 4; ++r)
          u[rt][r] = (col == 0) ? __expf(u[rt][r] - vm) : 1.0f;
    } else {
#pragma unroll
      for (int rt = 0; rt < 8; ++rt)
#pragma unroll
        for (int r = 0; r < 4; ++r) u[rt][r] = 1.0f;
    }
#pragma unroll
    for (int kt = 0; kt < 4; ++kt) {
      unsigned lo = (unsigned)__builtin_amdgcn_cvt_pk_fp8_f32(u[2*kt][0], u[2*kt][1], 0, false);
      lo = (unsigned)__builtin_amdgcn_cvt_pk_fp8_f32(u[2*kt][2], u[2*kt][3], (int)lo, true);
      unsigned hi = (unsigned)__builtin_amdgcn_cvt_pk_fp8_f32(u[2*kt+1][0], u[2*kt+1][1], 0, false);
      hi = (unsigned)__builtin_amdgcn_cvt_pk_fp8_f32(u[2*kt+1][2], u[2*kt+1][3], (int)hi, true);
      b[kt] = (long)(((unsigned long long)hi << 32) | lo);
    }
  }
  const int t0 = (gc == 0) ? 1 : (gc * LCH - BURN);
  float4 pf[2][8];
  {
    const float* e0 = emit + ((size_t)t0 << 7) + 4 * grp;
    const float* e1 = emit + ((size_t)(t0 + 1) << 7) + 4 * grp;
#pragma unroll
    for (int rt = 0; rt < 8; ++rt) {
      pf[0][rt] = *(const float4*)(e0 + 16 * rt);
      pf[1][rt] = *(const float4*)(e1 + 16 * rt);
    }
  }
  float acc = 0.f;
#pragma unroll
  for (int s = 0; s < NSTEP; ++s) {
    float e[8][4];
#pragma unroll
    for (int rt = 0; rt < 8; ++rt) {
      e[rt][0] = __expf(pf[s & 1][rt].x - C9);
      e[rt][1] = __expf(pf[s & 1][rt].y - C9);
      e[rt][2] = __expf(pf[s & 1][rt].z - C9);
      e[rt][3] = __expf(pf[s & 1][rt].w - C9);
    }
    if (s < NSTEP - 2) {
      const float* ep = emit + ((size_t)(t0 + s + 2) << 7) + 4 * grp;
#pragma unroll
      for (int rt = 0; rt < 8; ++rt) pf[s & 1][rt] = *(const float4*)(ep + 16 * rt);
    }
    f32x4 c[8];
#pragma unroll
    for (int rt = 0; rt < 8; ++rt) c[rt] = (f32x4){0.f, 0.f, 0.f, 0.f};
#pragma unroll
    for (int kt = 0; kt < 4; ++kt)
#pragma unroll
      for (int rt = 0; rt < 8; ++rt)
        c[rt] = __builtin_amdgcn_mfma_f32_16x16x32_fp8_fp8(a[rt][kt], b[kt], c[rt], 0, 0, 0);
    float wv[8][4];
    float vm = -1e30f;
#pragma unroll
    for (int rt = 0; rt < 8; ++rt)
#pragma unroll
      for (int r = 0; r < 4; ++r) {
        wv[rt][r] = c[rt][r] * e[rt][r];
        vm = fmaxf(vm, wv[rt][r]);
      }
    vm = fmaxf(vm, __shfl_xor(vm, 16, 64));
    vm = fmaxf(vm, __shfl_xor(vm, 32, 64));
    const bool on = (gc == 0) ? (s <= LCH - 2) : (s >= BURN);
    if (on) acc += __logf(vm);
    const float rinv = __frcp_rn(vm);
#pragma unroll
    for (int kt = 0; kt < 4; ++kt) {
      const float s0 = wv[2*kt][0] * rinv,   s1 = wv[2*kt][1] * rinv;
      const float s2 = wv[2*kt][2] * rinv,   s3 = wv[2*kt][3] * rinv;
      const float s4 = wv[2*kt+1][0] * rinv, s5 = wv[2*kt+1][1] * rinv;
      const float s6 = wv[2*kt+1][2] * rinv, s7 = wv[2*kt+1][3] * rinv;
      unsigned lo = (unsigned)__builtin_amdgcn_cvt_pk_fp8_f32(s0, s1, 0, false);
      lo = (unsigned)__builtin_amdgcn_cvt_pk_fp8_f32(s2, s3, (int)lo, true);
      unsigned hi = (unsigned)__builtin_amdgcn_cvt_pk_fp8_f32(s4, s5, 0, false);
      hi = (unsigned)__builtin_amdgcn_cvt_pk_fp8_f32(s6, s7, (int)hi, true);
      b[kt] = (long)(((unsigned long long)hi << 32) | lo);
    }
    if (s == NSTEP - 1 && gw == NWAVE - 1) {
      float lse = 0.f;
#pragma unroll
      for (int rt = 0; rt < 8; ++rt)
#pragma unroll
        for (int r = 0; r < 4; ++r)
          lse += (wv[rt][r] * rinv) * __expf(etrans[16 * rt + 4 * grp + r]);
      lse += __shfl_xor(lse, 16, 64);
      lse += __shfl_xor(lse, 32, 64);
      if (l == 15) atomicAdd(&ws[2], (double)lse);
    }
  }
  const float accf = acc + ((gc == 0) ? (m0 + (float)(LCH - 1) * C9)
                                      : ((float)LCH * C9));
  float av = (grp == 0) ? accf : 0.f;
#pragma unroll
  for (int off = 1; off < 64; off <<= 1) av += __shfl_xor(av, off, 64);
  if (l == 0) atomicAdd(&ws[0], (double)av);
}

__global__ void crf_score(const float* __restrict__ emit, const int* __restrict__ y,
                          const float* __restrict__ trans, const float* __restrict__ strans,
                          const float* __restrict__ etrans, double* __restrict__ ws)
{
  __shared__ float sred[4];
  int idx0 = blockIdx.x * 256 + threadIdx.x;
  float v = 0.f;
  for (int t = idx0; t < T_LEN - 1; t += NSCOREB * 256) {
    int yt = y[t], yn = y[t + 1];
    v += trans[yt * NTAG + yn] + emit[(size_t)t * NTAG + yt];
  }
  if (idx0 == 0) {
    int yl = y[T_LEN - 1];
    v += strans[y[0]] + etrans[yl] + emit[(size_t)(T_LEN - 1) * NTAG + yl];
  }
#pragma unroll
  for (int off = 1; off < 64; off <<= 1) v += __shfl_xor(v, off, 64);
  if ((threadIdx.x & 63) == 0) sred[threadIdx.x >> 6] = v;
  __syncthreads();
  if (threadIdx.x == 0)
    atomicAdd(&ws[1], (double)(sred[0] + sred[1] + sred[2] + sred[3]));
}

__global__ void crf_final(const double* __restrict__ ws, float* __restrict__ out)
{
  out[0] = (float)(ws[0] + log(ws[2]) - ws[1]);
}

// ---------------------------------------------------------------------------
extern "C" void kernel_launch(void* const* d_in, const int* in_sizes, int n_in,
                              void* d_out, int out_size, void* d_ws, size_t ws_size,
                              hipStream_t stream)
{
  const float* emit   = (const float*)d_in[0];
  const int*   y      = (const int*)d_in[1];
  const float* trans  = (const float*)d_in[2];
  const float* strans = (const float*)d_in[3];
  const float* etrans = (const float*)d_in[4];
  float*  out = (float*)d_out;
  double* ws  = (double*)d_ws;
  uint4*  q4  = (uint4*)((char*)d_ws + 128);             // 16 KB A-fragments
  unsigned* Ed = (unsigned*)((char*)d_ws + 128 + 16384); // 33.55 MB fp8 E

  const size_t need = 128 + 16384 + (size_t)T_LEN * NTAG;

  hipMemsetAsync(ws, 0, 8 * sizeof(double), stream);

  if (ws_size >= need) {
    crf_prep<<<dim3(NPREPB), dim3(256), 0, stream>>>(
        emit, y, trans, strans, etrans, Ed, q4, ws);
    crf_main<<<dim3(NFWDB), dim3(256), 0, stream>>>(
        emit, strans, etrans, (const unsigned char*)Ed, q4, ws, out);
  } else {
    crf_setup<<<dim3(1), dim3(64), 0, stream>>>(trans, q4);
    crf_score<<<dim3(NSCOREB), dim3(256), 0, stream>>>(emit, y, trans, strans, etrans, ws);
    crf_fwd  <<<dim3(NFWDB), dim3(256), 0, stream>>>(emit, strans, etrans, q4, ws);
    crf_final<<<dim3(1), dim3(1), 0, stream>>>(ws, out);
  }
}

// Round 14
// 120.918 us; speedup vs baseline: 1.6325x; 1.0326x over previous
//
#include <hip/hip_runtime.h>

typedef float f32x4 __attribute__((ext_vector_type(4)));

#define T_LEN   262144
#define NTAG    128
#define LCH     8
#define BURN    8
#define NSTEP   (LCH + BURN)       // 16
#define NCHUNK  (T_LEN / LCH)      // 32768
#define NWAVE   (NCHUNK / 16)      // 2048
#define NFWDB   (NWAVE / 4)        // 512
#define C9      6.23832462503951f  // 9 ln2 per-step scale
#define K63LN2  43.66827237527655f // 7 counted steps x 9ln2 (chunk 0)
#define K72LN2  49.90659700060892f // 8 counted steps x 9ln2

// ---------------------------------------------------------------------------
// Setup: A = fp8(exp(trans)) fragments.
// Byte j of tile (rt,kt): k = 32kt+4grp+(j&3)+16*(j>>2), row = 16rt+col.
// ---------------------------------------------------------------------------
__global__ void crf_setup(const float* __restrict__ trans, uint4* __restrict__ q4)
{
  const int l = threadIdx.x, col = l & 15, grp = l >> 4;
  for (int rt = 0; rt < 8; ++rt) {
    const int outtag = 16 * rt + col;
    for (int kp = 0; kp < 2; ++kp) {
      unsigned r[4];
      for (int h = 0; h < 2; ++h) {
        const int kt = kp * 2 + h;
        float q[8];
        for (int j = 0; j < 8; ++j) {
          const int k = 32 * kt + 4 * grp + (j & 3) + 16 * (j >> 2);
          q[j] = __expf(trans[k * NTAG + outtag]);
        }
        unsigned lo = (unsigned)__builtin_amdgcn_cvt_pk_fp8_f32(q[0], q[1], 0, false);
        lo = (unsigned)__builtin_amdgcn_cvt_pk_fp8_f32(q[2], q[3], (int)lo, true);
        unsigned hi = (unsigned)__builtin_amdgcn_cvt_pk_fp8_f32(q[4], q[5], 0, false);
        hi = (unsigned)__builtin_amdgcn_cvt_pk_fp8_f32(q[6], q[7], (int)hi, true);
        r[h * 2] = lo; r[h * 2 + 1] = hi;
      }
      q4[(rt * 2 + kp) * 64 + l] = make_uint4(r[0], r[1], r[2], r[3]);
    }
  }
}

// ---------------------------------------------------------------------------
// Single-pass: forward recurrence (R6/R10 structure, direct from emit) +
// folded score + ticket completion. One dispatch does everything.
// __launch_bounds__(256,4): 4 blocks/CU = 16 waves/CU (VGPR cap 128 >= 120).
// ---------------------------------------------------------------------------
__global__ __launch_bounds__(256, 4) void crf_all(
    const float* __restrict__ emit, const int* __restrict__ y,
    const float* __restrict__ trans, const float* __restrict__ strans,
    const float* __restrict__ etrans, const uint4* __restrict__ q4,
    double* __restrict__ ws, float* __restrict__ out)
{
  // XCD-bijective swizzle (NFWDB % 8 == 0): neighbor blocks share burn rows
  const int blk  = ((int)blockIdx.x & 7) * (NFWDB / 8) + ((int)blockIdx.x >> 3);
  const int w_id = threadIdx.x >> 6;
  const int l    = threadIdx.x & 63;
  const int col  = l & 15;
  const int grp  = l >> 4;
  const int gw   = blk * 4 + w_id;
  const int gc   = gw * 16 + col;

  // ---- A fragments: 16 coalesced dwordx4 loads (16 KB, L2-hot) ----
  long a[8][4];
#pragma unroll
  for (int rt = 0; rt < 8; ++rt)
#pragma unroll
    for (int kp = 0; kp < 2; ++kp) {
      uint4 v = q4[(rt * 2 + kp) * 64 + l];
      a[rt][2 * kp]     = (long)(((unsigned long long)v.y << 32) | v.x);
      a[rt][2 * kp + 1] = (long)(((unsigned long long)v.w << 32) | v.z);
    }

  // ---- init state: chunk 0 exact; others p = 1 ----
  float m0 = 0.f;
  long b[4];
  {
    float u[8][4];
    if (gw == 0) {
      float vm = -1e30f;
#pragma unroll
      for (int rt = 0; rt < 8; ++rt)
#pragma unroll
        for (int r = 0; r < 4; ++r) {
          const int tag = 16 * rt + 4 * grp + r;
          u[rt][r] = (col == 0) ? (strans[tag] + emit[tag]) : 0.f;
          vm = fmaxf(vm, u[rt][r]);
        }
      vm = fmaxf(vm, __shfl_xor(vm, 16, 64));
      vm = fmaxf(vm, __shfl_xor(vm, 32, 64));
      m0 = vm;                                 // col0 lanes: dc_0
#pragma unroll
      for (int rt = 0; rt < 8; ++rt)
#pragma unroll
        for (int r = 0; r < 4; ++r)
          u[rt][r] = (col == 0) ? __expf(u[rt][r] - vm) : 1.0f;
    } else {
#pragma unroll
      for (int rt = 0; rt < 8; ++rt)
#pragma unroll
        for (int r = 0; r < 4; ++r) u[rt][r] = 1.0f;
    }
#pragma unroll
    for (int kt = 0; kt < 4; ++kt) {
      unsigned lo = (unsigned)__builtin_amdgcn_cvt_pk_fp8_f32(u[2*kt][0], u[2*kt][1], 0, false);
      lo = (unsigned)__builtin_amdgcn_cvt_pk_fp8_f32(u[2*kt][2], u[2*kt][3], (int)lo, true);
      unsigned hi = (unsigned)__builtin_amdgcn_cvt_pk_fp8_f32(u[2*kt+1][0], u[2*kt+1][1], 0, false);
      hi = (unsigned)__builtin_amdgcn_cvt_pk_fp8_f32(u[2*kt+1][2], u[2*kt+1][3], (int)hi, true);
      b[kt] = (long)(((unsigned long long)hi << 32) | lo);
    }
  }

  // ---- depth-2 emit prefetch (step s consumes row t0+s) ----
  const int t0 = (gc == 0) ? 1 : (gc * LCH - BURN);
  float4 pf[2][8];
  {
    const float* e0 = emit + ((size_t)t0 << 7) + 4 * grp;
    const float* e1 = emit + ((size_t)(t0 + 1) << 7) + 4 * grp;
#pragma unroll
    for (int rt = 0; rt < 8; ++rt) {
      pf[0][rt] = *(const float4*)(e0 + 16 * rt);
      pf[1][rt] = *(const float4*)(e1 + 16 * rt);
    }
  }

  float acc = 0.f;

#pragma unroll
  for (int s = 0; s < NSTEP; ++s) {
    // e = exp(emit - 9ln2): off the recurrence path
    float e[8][4];
#pragma unroll
    for (int rt = 0; rt < 8; ++rt) {
      e[rt][0] = __expf(pf[s & 1][rt].x - C9);
      e[rt][1] = __expf(pf[s & 1][rt].y - C9);
      e[rt][2] = __expf(pf[s & 1][rt].z - C9);
      e[rt][3] = __expf(pf[s & 1][rt].w - C9);
    }
    if (s < NSTEP - 2) {
      const float* ep = emit + ((size_t)(t0 + s + 2) << 7) + 4 * grp;
#pragma unroll
      for (int rt = 0; rt < 8; ++rt) pf[s & 1][rt] = *(const float4*)(ep + 16 * rt);
    }

    // c = A x b
    f32x4 c[8];
#pragma unroll
    for (int rt = 0; rt < 8; ++rt) c[rt] = (f32x4){0.f, 0.f, 0.f, 0.f};
#pragma unroll
    for (int kt = 0; kt < 4; ++kt)
#pragma unroll
      for (int rt = 0; rt < 8; ++rt)
        c[rt] = __builtin_amdgcn_mfma_f32_16x16x32_fp8_fp8(a[rt][kt], b[kt], c[rt], 0, 0, 0);

    // w = c*e; per-step rescale; acc += log(max) on counted steps
    float wv[8][4];
    float vm = -1e30f;
#pragma unroll
    for (int rt = 0; rt < 8; ++rt)
#pragma unroll
      for (int r = 0; r < 4; ++r) {
        wv[rt][r] = c[rt][r] * e[rt][r];
        vm = fmaxf(vm, wv[rt][r]);
      }
    vm = fmaxf(vm, __shfl_xor(vm, 16, 64));
    vm = fmaxf(vm, __shfl_xor(vm, 32, 64));
    const bool on = (gc == 0) ? (s <= LCH - 2) : (s >= BURN);
    if (on) acc += __logf(vm);
    const float rinv = __frcp_rn(vm);
#pragma unroll
    for (int kt = 0; kt < 4; ++kt) {
      const float s0 = wv[2*kt][0] * rinv,   s1 = wv[2*kt][1] * rinv;
      const float s2 = wv[2*kt][2] * rinv,   s3 = wv[2*kt][3] * rinv;
      const float s4 = wv[2*kt+1][0] * rinv, s5 = wv[2*kt+1][1] * rinv;
      const float s6 = wv[2*kt+1][2] * rinv, s7 = wv[2*kt+1][3] * rinv;
      unsigned lo = (unsigned)__builtin_amdgcn_cvt_pk_fp8_f32(s0, s1, 0, false);
      lo = (unsigned)__builtin_amdgcn_cvt_pk_fp8_f32(s2, s3, (int)lo, true);
      unsigned hi = (unsigned)__builtin_amdgcn_cvt_pk_fp8_f32(s4, s5, 0, false);
      hi = (unsigned)__builtin_amdgcn_cvt_pk_fp8_f32(s6, s7, (int)hi, true);
      b[kt] = (long)(((unsigned long long)hi << 32) | lo);
    }

    if (s == NSTEP - 1 && gw == NWAVE - 1) {
      float lse = 0.f;
#pragma unroll
      for (int rt = 0; rt < 8; ++rt)
#pragma unroll
        for (int r = 0; r < 4; ++r)
          lse += (wv[rt][r] * rinv) * __expf(etrans[16 * rt + 4 * grp + r]);
      lse += __shfl_xor(lse, 16, 64);
      lse += __shfl_xor(lse, 32, 64);
      if (l == 15) atomicAdd(&ws[2], (double)lse);
    }
  }

  // per-chunk compensation for the 2^-9/step scaling on counted steps
  {
    const float accf = acc + ((gc == 0) ? (m0 + K63LN2) : K72LN2);
    float av = (grp == 0) ? accf : 0.f;
#pragma unroll
    for (int off = 1; off < 64; off <<= 1) av += __shfl_xor(av, off, 64);
    if (l == 0) atomicAdd(&ws[0], (double)av);
  }

  // ---- folded score: this block's 512 transitions ----
  {
    float sv = 0.f;
    const int base = (int)blockIdx.x * 512 + threadIdx.x;
#pragma unroll
    for (int ii = 0; ii < 2; ++ii) {
      const int t = base + 256 * ii;
      if (t < T_LEN - 1) {
        const int yt = y[t], yn = y[t + 1];
        sv += trans[yt * NTAG + yn] + emit[(size_t)t * NTAG + yt];
      }
    }
    if (blockIdx.x == 0 && threadIdx.x == 0) {
      const int yl = y[T_LEN - 1];
      sv += strans[y[0]] + etrans[yl] + emit[(size_t)(T_LEN - 1) * NTAG + yl];
    }
#pragma unroll
    for (int off = 1; off < 64; off <<= 1) sv += __shfl_xor(sv, off, 64);
    if (l == 0) atomicAdd(&ws[1], (double)sv);
  }

  // ---- completion ticket: last block writes the output ----
  __syncthreads();
  if (threadIdx.x == 0) {
    __threadfence();
    const unsigned t = atomicAdd((unsigned*)&ws[3], 1u);
    if (t == NFWDB - 1) {
      const double d0 = atomicAdd(&ws[0], 0.0);
      const double d1 = atomicAdd(&ws[1], 0.0);
      const double d2 = atomicAdd(&ws[2], 0.0);
      out[0] = (float)(d0 + log(d2) - d1);
    }
  }
}

// ---------------------------------------------------------------------------
extern "C" void kernel_launch(void* const* d_in, const int* in_sizes, int n_in,
                              void* d_out, int out_size, void* d_ws, size_t ws_size,
                              hipStream_t stream)
{
  const float* emit   = (const float*)d_in[0];
  const int*   y      = (const int*)d_in[1];
  const float* trans  = (const float*)d_in[2];
  const float* strans = (const float*)d_in[3];
  const float* etrans = (const float*)d_in[4];
  float*  out = (float*)d_out;
  double* ws  = (double*)d_ws;
  uint4*  q4  = (uint4*)((char*)d_ws + 128);   // 16 KB fp8 A-fragments

  hipMemsetAsync(ws, 0, 4 * sizeof(double), stream);
  crf_setup<<<dim3(1), dim3(64), 0, stream>>>(trans, q4);
  crf_all<<<dim3(NFWDB), dim3(256), 0, stream>>>(
      emit, y, trans, strans, etrans, q4, ws, out);
}